// Round 1
// baseline (820.021 us; speedup 1.0000x reference)
//
#include <hip/hip_runtime.h>

#define B_  64
#define C_  32
#define N_  1152
#define DI_ 8
#define DC_ 16
#define KBLK 256          // S grid (blocks)
#define SW   5            // waves per S block
#define STHREADS (SW*64)
#define SEG  (B_*C_*DC_)  // 32768 floats: one [b][i][c] slab

// S: recompute hat = W@x per (b,n), softmax over c via wave shuffles,
// block-local reduce over this block's n's into LDS, emit one partial slab.
// mode 0: write partial slab to partials[blk]; mode 1: atomicAdd into partials[0].
__global__ __launch_bounds__(STHREADS) void caps_s(
    const float* __restrict__ X, const float* __restrict__ W,
    const float* __restrict__ acc, float* __restrict__ partials,
    int t, int mode)
{
    __shared__ float s_lds[SEG];           // [b][i][c] : bank = c (2-way free)
    const int tid = threadIdx.x;
    float4* sz = (float4*)s_lds;
    for (int idx = tid; idx < SEG/4; idx += STHREADS) sz[idx] = make_float4(0.f,0.f,0.f,0.f);
    __syncthreads();

    const int w    = tid >> 6;
    const int lane = tid & 63;
    const int c    = lane & 31;
    const int h    = lane >> 5;            // i-half: i = h*8 + k
    const int n    = w * 256 + blockIdx.x; // balanced wave->n map

    if (n < N_) {
        // W[c][n][i][j]: 64 consecutive floats for this lane's (c, i-half)
        const float4* wp = (const float4*)(W + (size_t)(c*N_ + n)*128 + h*64);
        float4 wr[16];
#pragma unroll
        for (int q = 0; q < 16; q++) wr[q] = wp[q];

        for (int bb = 0; bb < B_; bb++) {
            const int b = (bb + w*13) & 63;              // stagger waves across b
            const float4* xp = (const float4*)(X + (size_t)(b*N_ + n)*DI_);
            const float4 xa = xp[0], xb = xp[1];
            float hat[8];
#pragma unroll
            for (int k = 0; k < 8; k++) {
                const float4 wa = wr[2*k], wb = wr[2*k+1];
                hat[k] = wa.x*xa.x + wa.y*xa.y + wa.z*xa.z + wa.w*xa.w
                       + wb.x*xb.x + wb.y*xb.y + wb.z*xb.z + wb.w*xb.w;
            }
            float softc;
            if (t > 0) {
                const float4* ap = (const float4*)(acc + ((b*C_ + c)*DC_ + h*8));
                const float4 a0 = ap[0], a1 = ap[1];
                float lg = hat[0]*a0.x + hat[1]*a0.y + hat[2]*a0.z + hat[3]*a0.w
                         + hat[4]*a1.x + hat[5]*a1.y + hat[6]*a1.z + hat[7]*a1.w;
                lg += __shfl_xor(lg, 32, 64);            // combine i-halves
                float m = lg;
#pragma unroll
                for (int msk = 16; msk >= 1; msk >>= 1) m = fmaxf(m, __shfl_xor(m, msk, 64));
                const float e = __expf(lg - m);
                float ssum = e;
#pragma unroll
                for (int msk = 16; msk >= 1; msk >>= 1) ssum += __shfl_xor(ssum, msk, 64);
                softc = e / ssum;
            } else {
                softc = 1.0f / 32.0f;                    // softmax(0) over C=32
            }
#pragma unroll
            for (int k = 0; k < 8; k++)
                atomicAdd(&s_lds[b*512 + (h*8+k)*32 + c], softc * hat[k]);
        }
    }
    __syncthreads();

    if (mode == 0) {
        float4* pout = (float4*)(partials + (size_t)blockIdx.x * SEG);
        for (int idx = tid; idx < SEG/4; idx += STHREADS) pout[idx] = sz[idx];
    } else {
        for (int idx = tid; idx < SEG; idx += STHREADS)
            atomicAdd(&partials[idx], s_lds[idx]);
    }
}

// R: per-b block. Reduce K partial slabs, squash, update acc (or write out at t==2).
__global__ __launch_bounds__(512) void caps_r(
    float* __restrict__ partials, int K, int zero_after,
    float* __restrict__ acc, float* __restrict__ out, int t)
{
    __shared__ float v_lds[C_*DC_];
    __shared__ float scale[C_];
    const int b = blockIdx.x;
    const int e = threadIdx.x;             // e = i*32 + c
    float v = 0.f;
    float* p = partials + b*(C_*DC_) + e;
#pragma unroll 8
    for (int q = 0; q < K; q++) v += p[(size_t)q * SEG];
    if (zero_after) p[0] = 0.f;            // re-zero slab for next iteration (atomic path)
    v_lds[e] = v;
    __syncthreads();
    if (e < C_) {
        float sq = 0.f;
#pragma unroll
        for (int i = 0; i < DC_; i++) { const float z = v_lds[i*32 + e]; sq += z*z; }
        scale[e] = sq / (1.f + sq) * rsqrtf(sq + 1e-7f);
    }
    __syncthreads();
    const int c = e & 31, i = e >> 5;
    const float ov = v * scale[c];
    const int oidx = (b*C_ + c)*DC_ + i;
    if (t == 2) out[oidx] = ov;
    else        acc[oidx] = (t == 0) ? ov : (acc[oidx] + ov);
}

extern "C" void kernel_launch(void* const* d_in, const int* in_sizes, int n_in,
                              void* d_out, int out_size, void* d_ws, size_t ws_size,
                              hipStream_t stream) {
    const float* X = (const float*)d_in[0];   // [B,N,DI]
    const float* W = (const float*)d_in[1];   // [C,N,DC,DI]
    float* out = (float*)d_out;               // [B,C,DC]

    const size_t need_big = ((size_t)KBLK * SEG + SEG) * sizeof(float); // partials + acc
    if (ws_size >= need_big) {
        float* partials = (float*)d_ws;
        float* acc = partials + (size_t)KBLK * SEG;
        for (int t = 0; t < 3; t++) {
            caps_s<<<KBLK, STHREADS, 0, stream>>>(X, W, acc, partials, t, 0);
            caps_r<<<B_, 512, 0, stream>>>(partials, KBLK, 0, acc, out, t);
        }
    } else {
        // small-ws fallback: single atomically-accumulated slab
        float* sbuf = (float*)d_ws;           // [SEG]
        float* acc  = sbuf + SEG;             // [SEG]
        hipMemsetAsync(sbuf, 0, SEG * sizeof(float), stream);
        for (int t = 0; t < 3; t++) {
            caps_s<<<KBLK, STHREADS, 0, stream>>>(X, W, acc, sbuf, t, 1);
            caps_r<<<B_, 512, 0, stream>>>(sbuf, 1, 1, acc, out, t);
        }
    }
}

// Round 2
// 441.747 us; speedup vs baseline: 1.8563x; 1.8563x over previous
//
#include <hip/hip_runtime.h>

#define B_  64
#define C_  32
#define N_  1152
#define DI_ 8
#define DC_ 16
#define FRS 68               // W frag stride (64 floats + 4 pad -> b128 reads hit all 8 bank-groups)
#define NCH 4                // n's per staged chunk
#define STH 512              // S block threads (8 waves)

// S: block = (b-half 32 b's) x (4-n chunk[s]). Stage W+X in LDS once per chunk,
// then barrier-free loop: each wave owns 4 b's, accumulates acc[4][8] in REGISTERS
// over the chunk's n's (no atomics anywhere). One partial slab [32][512] per block.
__global__ __launch_bounds__(STH, 4) void caps_s(
    const float* __restrict__ X, const float* __restrict__ W,
    const float* __restrict__ aout, float* __restrict__ partials,
    int t, int niter)
{
    __shared__ float wlds[NCH * 64 * FRS];   // [nl][frag=2c+h][68]
    __shared__ float xlds[NCH * 32 * 8];     // [nl][b_local][8]

    const int CHN   = gridDim.x >> 1;        // chunks per b-half
    const int chunk = blockIdx.x >> 1;
    const int bh    = blockIdx.x & 1;
    const int b0    = bh * 32;
    const int tid   = threadIdx.x;
    const int w     = tid >> 6;
    const int lane  = tid & 63;
    const int c     = lane & 31;
    const int h     = lane >> 5;

    float acc[4][8];
#pragma unroll
    for (int bq = 0; bq < 4; bq++)
#pragma unroll
        for (int r = 0; r < 8; r++) acc[bq][r] = 0.f;

    for (int cc = 0; cc < niter; cc++) {
        if (cc) __syncthreads();                       // drain readers before re-stage
        const int n0 = (chunk + cc * CHN) * NCH;

        // stage W: granule G -> (nl, frag f=2c+h, quad q); 64-float frags are
        // contiguous in global W ([c][n][128] = frag(c,0)++frag(c,1))
        for (int G = tid; G < NCH * 1024; G += STH) {
            const int nl = G >> 10, f = (G >> 4) & 63, q = G & 15;
            const int wc = f >> 1, wh = f & 1;
            const float4 v = *(const float4*)(W + (size_t)(wc * N_ + n0 + nl) * 128 + wh * 64 + q * 4);
            *(float4*)(wlds + (nl * 64 + f) * FRS + q * 4) = v;
        }
        // stage X
        for (int G = tid; G < NCH * 64; G += STH) {
            const int nl = G >> 6, bl = (G >> 1) & 31, qx = G & 1;
            const float4 v = *(const float4*)(X + (size_t)((b0 + bl) * N_ + n0 + nl) * DI_ + qx * 4);
            *(float4*)(xlds + (nl * 32 + bl) * 8 + qx * 4) = v;
        }
        __syncthreads();

#pragma unroll
        for (int nl = 0; nl < NCH; nl++) {
            float4 xa[4], xb[4];
#pragma unroll
            for (int bq = 0; bq < 4; bq++) {
                const float* xp = xlds + (nl * 32 + (w * 4 + bq)) * 8;  // broadcast reads
                xa[bq] = *(const float4*)xp;
                xb[bq] = *(const float4*)(xp + 4);
            }
            float hat[4][8];
            const float* frag = wlds + (nl * 64 + 2 * c + h) * FRS;
#pragma unroll
            for (int r = 0; r < 8; r++) {
                const float4 wa = *(const float4*)(frag + r * 8);
                const float4 wb = *(const float4*)(frag + r * 8 + 4);
#pragma unroll
                for (int bq = 0; bq < 4; bq++) {
                    hat[bq][r] = wa.x * xa[bq].x + wa.y * xa[bq].y + wa.z * xa[bq].z + wa.w * xa[bq].w
                               + wb.x * xb[bq].x + wb.y * xb[bq].y + wb.z * xb[bq].z + wb.w * xb[bq].w;
                }
            }
#pragma unroll
            for (int bq = 0; bq < 4; bq++) {
                float softc;
                if (t > 0) {
                    const int b = b0 + w * 4 + bq;
                    const float* ap = aout + (size_t)(b * C_ + c) * DC_ + h * 8;
                    const float4 a0 = *(const float4*)ap;
                    const float4 a1 = *(const float4*)(ap + 4);
                    float lg = hat[bq][0] * a0.x + hat[bq][1] * a0.y + hat[bq][2] * a0.z + hat[bq][3] * a0.w
                             + hat[bq][4] * a1.x + hat[bq][5] * a1.y + hat[bq][6] * a1.z + hat[bq][7] * a1.w;
                    lg += __shfl_xor(lg, 32, 64);      // combine i-halves (lane^32 = same c)
                    // no max-subtract: |logit| <= ~6 (||out||<1 per squash, 2 routing rounds)
                    const float e = __expf(lg);
                    float s = e;
#pragma unroll
                    for (int m = 16; m >= 1; m >>= 1) s += __shfl_xor(s, m, 64);
                    softc = e / s;
                } else {
                    softc = 1.0f / 32.0f;              // softmax(0) over C=32
                }
#pragma unroll
                for (int r = 0; r < 8; r++) acc[bq][r] += softc * hat[bq][r];
            }
        }
    }

    // slab = bh*CHN + chunk; e-layout [c][i], i = h*8+r
    float* pout = partials + ((size_t)(bh * CHN + chunk) * 32) * 512;
#pragma unroll
    for (int bq = 0; bq < 4; bq++) {
        float* pb = pout + (w * 4 + bq) * 512 + c * 16 + h * 8;
        *(float4*)pb       = make_float4(acc[bq][0], acc[bq][1], acc[bq][2], acc[bq][3]);
        *(float4*)(pb + 4) = make_float4(acc[bq][4], acc[bq][5], acc[bq][6], acc[bq][7]);
    }
}

// R: block = (b, e-quarter). Thread pair (e, parity) splits the chunk-sum;
// squash via in-wave shuffles (c-group = 32 lanes). Updates running acc_out,
// writes d_out at t==2.
__global__ __launch_bounds__(256) void caps_r(
    const float* __restrict__ partials, float* __restrict__ accb,
    float* __restrict__ out, int t, int CH)
{
    const int b   = blockIdx.x >> 2;
    const int q   = blockIdx.x & 3;
    const int tid = threadIdx.x;
    const int e   = q * 128 + (tid >> 1);
    const int p   = tid & 1;
    const int bl  = b & 31;
    const float* base = partials + ((size_t)((b >> 5) * CH) * 32 + bl) * 512 + e;
    float v = 0.f;
#pragma unroll 8
    for (int ch = p; ch < CH; ch += 2)
        v += base[(size_t)ch * 16384];
    v += __shfl_xor(v, 1, 64);                 // combine parities
    float sq = v * v;
#pragma unroll
    for (int m = 2; m <= 16; m <<= 1) sq += __shfl_xor(sq, m, 64);  // sum over i (16 e's of this c)
    const float scale = sq / (1.f + sq) * rsqrtf(sq + 1e-7f);
    const float ov = v * scale;
    if (p == 0) {
        const int oidx = b * 512 + e;
        if (t == 2) out[oidx] = ov;
        else        accb[oidx] = (t == 0) ? ov : (accb[oidx] + ov);
    }
}

extern "C" void kernel_launch(void* const* d_in, const int* in_sizes, int n_in,
                              void* d_out, int out_size, void* d_ws, size_t ws_size,
                              hipStream_t stream) {
    const float* X = (const float*)d_in[0];   // [B,N,DI]
    const float* W = (const float*)d_in[1];   // [C,N,DC,DI]
    float* out = (float*)d_out;               // [B,C,DC]

    // fast path: 576 blocks (1 chunk each) -> 576 slabs = 37.75 MB partials
    int grid_s = 576, niter = 1;
    size_t need = ((size_t)576 * 16384 + 32768) * sizeof(float);
    if (ws_size < need) { grid_s = 288; niter = 2; }   // 288 slabs = 18.9 MB
    const int CHN = grid_s >> 1;

    float* partials = (float*)d_ws;
    float* accb = partials + (size_t)grid_s * 16384;

    for (int t = 0; t < 3; t++) {
        caps_s<<<grid_s, STH, 0, stream>>>(X, W, accb, partials, t, niter);
        caps_r<<<256, 256, 0, stream>>>(partials, accb, out, t, CHN);
    }
}

// Round 3
// 280.716 us; speedup vs baseline: 2.9212x; 1.5736x over previous
//
#include <hip/hip_runtime.h>

#define B_  64
#define C_  32
#define N_  1152
#define DI_ 8
#define DC_ 16
#define FRS 68               // W frag stride (64 floats + 4 pad -> b128 reads hit all 8 bank-groups)
#define NCH 4                // n's per staged chunk
#define STH 512              // S block threads (8 waves)

// S: block = (b-half 32 b's) x (4-n chunk[s]). Stage W+X in LDS once per chunk,
// then barrier-free loop: each wave owns 4 b's, accumulates acc[4][8] in REGISTERS
// over the chunk's n's (no atomics anywhere). One partial slab [32][512] per block.
// launch_bounds (512,2): 128-VGPR budget. (512,4)=64 VGPRs spilled ~300 MB/dispatch
// to scratch (R2: FETCH 130MB, WRITE 252MB vs ~40MB ideal).
__global__ __launch_bounds__(STH, 2) void caps_s(
    const float* __restrict__ X, const float* __restrict__ W,
    const float* __restrict__ aout, float* __restrict__ partials,
    int t, int niter)
{
    __shared__ float wlds[NCH * 64 * FRS];   // [nl][frag=2c+h][68]
    __shared__ float xlds[NCH * 32 * 8];     // [nl][b_local][8]

    const int CHN   = gridDim.x >> 1;        // chunks per b-half
    const int chunk = blockIdx.x >> 1;
    const int bh    = blockIdx.x & 1;
    const int b0    = bh * 32;
    const int tid   = threadIdx.x;
    const int w     = tid >> 6;
    const int lane  = tid & 63;
    const int c     = lane & 31;
    const int h     = lane >> 5;

    float acc[4][8];
#pragma unroll
    for (int bq = 0; bq < 4; bq++)
#pragma unroll
        for (int r = 0; r < 8; r++) acc[bq][r] = 0.f;

    for (int cc = 0; cc < niter; cc++) {
        if (cc) __syncthreads();                       // drain readers before re-stage
        const int n0 = (chunk + cc * CHN) * NCH;

        // stage W: granule G -> (nl, frag f=2c+h, quad q); 64-float frags are
        // contiguous in global W ([c][n][128] = frag(c,0)++frag(c,1))
        for (int G = tid; G < NCH * 1024; G += STH) {
            const int nl = G >> 10, f = (G >> 4) & 63, q = G & 15;
            const int wc = f >> 1, wh = f & 1;
            const float4 v = *(const float4*)(W + (size_t)(wc * N_ + n0 + nl) * 128 + wh * 64 + q * 4);
            *(float4*)(wlds + (nl * 64 + f) * FRS + q * 4) = v;
        }
        // stage X
        for (int G = tid; G < NCH * 64; G += STH) {
            const int nl = G >> 6, bl = (G >> 1) & 31, qx = G & 1;
            const float4 v = *(const float4*)(X + (size_t)((b0 + bl) * N_ + n0 + nl) * DI_ + qx * 4);
            *(float4*)(xlds + (nl * 32 + bl) * 8 + qx * 4) = v;
        }
        __syncthreads();

#pragma unroll
        for (int nl = 0; nl < NCH; nl++) {
            float4 xa[4], xb[4];
#pragma unroll
            for (int bq = 0; bq < 4; bq++) {
                const float* xp = xlds + (nl * 32 + (w * 4 + bq)) * 8;  // broadcast reads
                xa[bq] = *(const float4*)xp;
                xb[bq] = *(const float4*)(xp + 4);
            }
            float hat[4][8];
            const float* frag = wlds + (nl * 64 + 2 * c + h) * FRS;
#pragma unroll
            for (int r = 0; r < 8; r++) {
                const float4 wa = *(const float4*)(frag + r * 8);
                const float4 wb = *(const float4*)(frag + r * 8 + 4);
#pragma unroll
                for (int bq = 0; bq < 4; bq++) {
                    hat[bq][r] = wa.x * xa[bq].x + wa.y * xa[bq].y + wa.z * xa[bq].z + wa.w * xa[bq].w
                               + wb.x * xb[bq].x + wb.y * xb[bq].y + wb.z * xb[bq].z + wb.w * xb[bq].w;
                }
            }
#pragma unroll
            for (int bq = 0; bq < 4; bq++) {
                float softc;
                if (t > 0) {
                    const int b = b0 + w * 4 + bq;
                    const float* ap = aout + (size_t)(b * C_ + c) * DC_ + h * 8;
                    const float4 a0 = *(const float4*)ap;
                    const float4 a1 = *(const float4*)(ap + 4);
                    float lg = hat[bq][0] * a0.x + hat[bq][1] * a0.y + hat[bq][2] * a0.z + hat[bq][3] * a0.w
                             + hat[bq][4] * a1.x + hat[bq][5] * a1.y + hat[bq][6] * a1.z + hat[bq][7] * a1.w;
                    lg += __shfl_xor(lg, 32, 64);      // combine i-halves (lane^32 = same c)
                    // no max-subtract: |logit| <= ~6 (||out||<1 per squash, 2 routing rounds)
                    const float e = __expf(lg);
                    float s = e;
#pragma unroll
                    for (int m = 16; m >= 1; m >>= 1) s += __shfl_xor(s, m, 64);
                    softc = e / s;
                } else {
                    softc = 1.0f / 32.0f;              // softmax(0) over C=32
                }
#pragma unroll
                for (int r = 0; r < 8; r++) acc[bq][r] += softc * hat[bq][r];
            }
        }
    }

    // slab = bh*CHN + chunk; e-layout [c][i], i = h*8+r
    float* pout = partials + ((size_t)(bh * CHN + chunk) * 32) * 512;
#pragma unroll
    for (int bq = 0; bq < 4; bq++) {
        float* pb = pout + (w * 4 + bq) * 512 + c * 16 + h * 8;
        *(float4*)pb       = make_float4(acc[bq][0], acc[bq][1], acc[bq][2], acc[bq][3]);
        *(float4*)(pb + 4) = make_float4(acc[bq][4], acc[bq][5], acc[bq][6], acc[bq][7]);
    }
}

// R: block = (b, e-quarter). Thread pair (e, parity) splits the chunk-sum;
// squash via in-wave shuffles (c-group = 32 lanes). Updates running acc_out,
// writes d_out at t==2.
__global__ __launch_bounds__(256) void caps_r(
    const float* __restrict__ partials, float* __restrict__ accb,
    float* __restrict__ out, int t, int CH)
{
    const int b   = blockIdx.x >> 2;
    const int q   = blockIdx.x & 3;
    const int tid = threadIdx.x;
    const int e   = q * 128 + (tid >> 1);
    const int p   = tid & 1;
    const int bl  = b & 31;
    const float* base = partials + ((size_t)((b >> 5) * CH) * 32 + bl) * 512 + e;
    float v = 0.f;
#pragma unroll 8
    for (int ch = p; ch < CH; ch += 2)
        v += base[(size_t)ch * 16384];
    v += __shfl_xor(v, 1, 64);                 // combine parities
    float sq = v * v;
#pragma unroll
    for (int m = 2; m <= 16; m <<= 1) sq += __shfl_xor(sq, m, 64);  // sum over i (16 e's of this c)
    const float scale = sq / (1.f + sq) * rsqrtf(sq + 1e-7f);
    const float ov = v * scale;
    if (p == 0) {
        const int oidx = b * 512 + e;
        if (t == 2) out[oidx] = ov;
        else        accb[oidx] = (t == 0) ? ov : (accb[oidx] + ov);
    }
}

extern "C" void kernel_launch(void* const* d_in, const int* in_sizes, int n_in,
                              void* d_out, int out_size, void* d_ws, size_t ws_size,
                              hipStream_t stream) {
    const float* X = (const float*)d_in[0];   // [B,N,DI]
    const float* W = (const float*)d_in[1];   // [C,N,DC,DI]
    float* out = (float*)d_out;               // [B,C,DC]

    // fast path: 576 blocks (1 chunk each) -> 576 slabs = 37.75 MB partials
    int grid_s = 576, niter = 1;
    size_t need = ((size_t)576 * 16384 + 32768) * sizeof(float);
    if (ws_size < need) { grid_s = 288; niter = 2; }   // 288 slabs = 18.9 MB
    const int CHN = grid_s >> 1;

    float* partials = (float*)d_ws;
    float* accb = partials + (size_t)grid_s * 16384;

    for (int t = 0; t < 3; t++) {
        caps_s<<<grid_s, STH, 0, stream>>>(X, W, accb, partials, t, niter);
        caps_r<<<256, 256, 0, stream>>>(partials, accb, out, t, CHN);
    }
}

// Round 4
// 256.067 us; speedup vs baseline: 3.2024x; 1.0963x over previous
//
#include <hip/hip_runtime.h>

#define B_  64
#define C_  32
#define N_  1152
#define DI_ 8
#define DC_ 16
#define FRS 68               // W frag stride (64 + 4 pad -> b128 reads spread over bank groups)
#define NCH 3                // n's per staged chunk
#define NSLOT 128            // chunk-slots; each handles chunks slot, slot+128, slot+256
#define STH 512              // 8 waves

// S: block = (b-group of 16 b's) x (chunk-slot). 512 blocks = exactly 2/CU.
// Wave owns 2 b's (bq=2): live set ~85 regs -> no spills under the 128 cap
// (R3: bq=4 live ~110 under cap 128 still spilled ~50 MB/dispatch).
// aout fragments hoisted out of the n-loop ((b,c)-invariant).
__global__ __launch_bounds__(STH, 2) void caps_s(
    const float* __restrict__ X, const float* __restrict__ W,
    const float* __restrict__ aout, float* __restrict__ partials, int t)
{
    __shared__ float wlds[NCH * 64 * FRS];   // 52,224 B : [nl][frag=2c+h][68]
    __shared__ float xlds[NCH * 16 * 8];     //  1,536 B : [nl][b_local][8]

    const int bg   = blockIdx.x & 3;
    const int slot = blockIdx.x >> 2;
    const int tid  = threadIdx.x;
    const int w    = tid >> 6;
    const int lane = tid & 63;
    const int c    = lane & 31;
    const int h    = lane >> 5;
    const int bl0  = w * 2;                  // wave's local b's: bl0, bl0+1

    float areg[2][8] = {};
    if (t > 0) {
#pragma unroll
        for (int bq = 0; bq < 2; bq++) {
            const float* ap = aout + (size_t)(bg * 16 + bl0 + bq) * 512 + c * 16 + h * 8;
            const float4 a0 = *(const float4*)ap;
            const float4 a1 = *(const float4*)(ap + 4);
            areg[bq][0]=a0.x; areg[bq][1]=a0.y; areg[bq][2]=a0.z; areg[bq][3]=a0.w;
            areg[bq][4]=a1.x; areg[bq][5]=a1.y; areg[bq][6]=a1.z; areg[bq][7]=a1.w;
        }
    }

    float acc[2][8];
#pragma unroll
    for (int bq = 0; bq < 2; bq++)
#pragma unroll
        for (int r = 0; r < 8; r++) acc[bq][r] = 0.f;

    for (int cc = 0; cc < 3; cc++) {
        if (cc) __syncthreads();             // drain readers before re-stage
        const int n0 = (slot + cc * NSLOT) * NCH;

        // stage W: granule -> (nl, frag f=2c+h, quad q); frags contiguous in W
        for (int G = tid; G < NCH * 1024; G += STH) {
            const int nl = G >> 10, f = (G >> 4) & 63, q = G & 15;
            const int wc = f >> 1, wh = f & 1;
            const float4 v = *(const float4*)(W + (size_t)(wc * N_ + n0 + nl) * 128 + wh * 64 + q * 4);
            *(float4*)(wlds + (nl * 64 + f) * FRS + q * 4) = v;
        }
        // stage X: 16 b's x NCH n's
        if (tid < NCH * 32) {
            const int nl = tid >> 5, bl = (tid >> 1) & 15, qx = tid & 1;
            const float4 v = *(const float4*)(X + (size_t)((bg * 16 + bl) * N_ + n0 + nl) * DI_ + qx * 4);
            *(float4*)(xlds + (nl * 16 + bl) * 8 + qx * 4) = v;
        }
        __syncthreads();

#pragma unroll
        for (int nl = 0; nl < NCH; nl++) {
            float4 xa[2], xb[2];
#pragma unroll
            for (int bq = 0; bq < 2; bq++) {
                const float* xp = xlds + (nl * 16 + bl0 + bq) * 8;   // wave-uniform: broadcast
                xa[bq] = *(const float4*)xp;
                xb[bq] = *(const float4*)(xp + 4);
            }
            float hat[2][8];
            const float* frag = wlds + (nl * 64 + 2 * c + h) * FRS;
#pragma unroll
            for (int r = 0; r < 8; r++) {
                const float4 wa = *(const float4*)(frag + r * 8);
                const float4 wb = *(const float4*)(frag + r * 8 + 4);
#pragma unroll
                for (int bq = 0; bq < 2; bq++) {
                    hat[bq][r] = wa.x * xa[bq].x + wa.y * xa[bq].y + wa.z * xa[bq].z + wa.w * xa[bq].w
                               + wb.x * xb[bq].x + wb.y * xb[bq].y + wb.z * xb[bq].z + wb.w * xb[bq].w;
                }
            }
#pragma unroll
            for (int bq = 0; bq < 2; bq++) {
                float softc;
                if (t > 0) {
                    float lg = hat[bq][0]*areg[bq][0] + hat[bq][1]*areg[bq][1]
                             + hat[bq][2]*areg[bq][2] + hat[bq][3]*areg[bq][3]
                             + hat[bq][4]*areg[bq][4] + hat[bq][5]*areg[bq][5]
                             + hat[bq][6]*areg[bq][6] + hat[bq][7]*areg[bq][7];
                    lg += __shfl_xor(lg, 32, 64);      // combine i-halves (lane^32 = same c)
                    // no max-subtract: |logit| <= ~12 (||out_t||<1 per squash)
                    const float e = __expf(lg);
                    float s = e;
#pragma unroll
                    for (int m = 16; m >= 1; m >>= 1) s += __shfl_xor(s, m, 64);
                    softc = e / s;
                } else {
                    softc = 1.0f / 32.0f;              // softmax(0) over C=32
                }
#pragma unroll
                for (int r = 0; r < 8; r++) acc[bq][r] += softc * hat[bq][r];
            }
        }
    }

    // slab = bg*NSLOT + slot : [16 b][512], e = c*16 + (h*8+r)
    float* pout = partials + (size_t)(bg * NSLOT + slot) * (16 * 512);
#pragma unroll
    for (int bq = 0; bq < 2; bq++) {
        float* pb = pout + (bl0 + bq) * 512 + c * 16 + h * 8;
        *(float4*)pb       = make_float4(acc[bq][0], acc[bq][1], acc[bq][2], acc[bq][3]);
        *(float4*)(pb + 4) = make_float4(acc[bq][4], acc[bq][5], acc[bq][6], acc[bq][7]);
    }
}

// R: block = (b, e-quarter). Thread pair (e, parity) splits the slot-sum;
// squash via in-wave shuffles. Updates running acc_out; writes d_out at t==2.
__global__ __launch_bounds__(256) void caps_r(
    const float* __restrict__ partials, float* __restrict__ accb,
    float* __restrict__ out, int t)
{
    const int b   = blockIdx.x >> 2;
    const int q   = blockIdx.x & 3;
    const int tid = threadIdx.x;
    const int e   = q * 128 + (tid >> 1);
    const int p   = tid & 1;
    const int bg  = b >> 4, bl = b & 15;
    const float* base = partials + (size_t)bg * NSLOT * 8192 + (size_t)bl * 512 + e;
    float v = 0.f;
#pragma unroll 8
    for (int ch = p; ch < NSLOT; ch += 2)
        v += base[(size_t)ch * 8192];
    v += __shfl_xor(v, 1, 64);                 // combine parities
    float sq = v * v;
#pragma unroll
    for (int m = 2; m <= 16; m <<= 1) sq += __shfl_xor(sq, m, 64);  // sum over i within c
    const float scale = sq / (1.f + sq) * rsqrtf(sq + 1e-7f);
    const float ov = v * scale;
    if (p == 0) {
        const int oidx = b * 512 + e;
        if (t == 2) out[oidx] = ov;
        else        accb[oidx] = (t == 0) ? ov : (accb[oidx] + ov);
    }
}

extern "C" void kernel_launch(void* const* d_in, const int* in_sizes, int n_in,
                              void* d_out, int out_size, void* d_ws, size_t ws_size,
                              hipStream_t stream) {
    const float* X = (const float*)d_in[0];   // [B,N,DI]
    const float* W = (const float*)d_in[1];   // [C,N,DC,DI]
    float* out = (float*)d_out;               // [B,C,DC]

    // 512 slabs x 32 KB = 16.8 MB partials + 128 KB acc (R3 path used 37.9 MB OK)
    float* partials = (float*)d_ws;
    float* accb = partials + (size_t)512 * 8192;

    for (int t = 0; t < 3; t++) {
        caps_s<<<512, STH, 0, stream>>>(X, W, accb, partials, t);
        caps_r<<<256, 256, 0, stream>>>(partials, accb, out, t);
    }
}

// Round 5
// 211.715 us; speedup vs baseline: 3.8732x; 1.2095x over previous
//
#include <hip/hip_runtime.h>

#define B_  64
#define C_  32
#define N_  1152
#define DI_ 8
#define DC_ 16
#define NCH 3                // n's per staged chunk
#define NSLOT 128            // chunk-slots; each handles chunks slot, slot+128, slot+256
#define STH 512              // 8 waves

// S: block = (b-group of 16 b's) x (chunk-slot). 512 blocks = exactly 2/CU.
// Wave owns 2 b's; acc in registers (VGPR 96, no spills — R4).
// W frag LDS layout: [nl][f=2c+h][16 quads], quad q stored at physical quad
// q ^ (c&7). Unswizzled (R4, stride 68) every frag read was an 8-way bank
// conflict (12.2M conflict cycles/dispatch): base bank 4*(f+2r) mod 32 hits
// only 8 of 32 banks across the wave. The XOR spreads any 8 consecutive
// lanes over all 32 banks -> conflict-free.
__global__ __launch_bounds__(STH, 2) void caps_s(
    const float* __restrict__ X, const float* __restrict__ W,
    const float* __restrict__ aout, float* __restrict__ partials, int t)
{
    __shared__ float wlds[NCH * 64 * 64];    // 49,152 B : [nl][f][phys quad]
    __shared__ float xlds[NCH * 16 * 8];     //  1,536 B : [nl][b_local][8]

    const int bg   = blockIdx.x & 3;
    const int slot = blockIdx.x >> 2;
    const int tid  = threadIdx.x;
    const int w    = tid >> 6;
    const int lane = tid & 63;
    const int c    = lane & 31;
    const int h    = lane >> 5;
    const int bl0  = w * 2;                  // wave's local b's: bl0, bl0+1
    const int sw   = c & 7;                  // frag quad swizzle key

    float areg[2][8] = {};
    if (t > 0) {
#pragma unroll
        for (int bq = 0; bq < 2; bq++) {
            const float* ap = aout + (size_t)(bg * 16 + bl0 + bq) * 512 + c * 16 + h * 8;
            const float4 a0 = *(const float4*)ap;
            const float4 a1 = *(const float4*)(ap + 4);
            areg[bq][0]=a0.x; areg[bq][1]=a0.y; areg[bq][2]=a0.z; areg[bq][3]=a0.w;
            areg[bq][4]=a1.x; areg[bq][5]=a1.y; areg[bq][6]=a1.z; areg[bq][7]=a1.w;
        }
    }

    float acc[2][8];
#pragma unroll
    for (int bq = 0; bq < 2; bq++)
#pragma unroll
        for (int r = 0; r < 8; r++) acc[bq][r] = 0.f;

    for (int cc = 0; cc < 3; cc++) {
        if (cc) __syncthreads();             // drain readers before re-stage
        const int n0 = (slot + cc * NSLOT) * NCH;

        // stage W: granule -> (nl, f=2c+h, quad q) at phys quad q^(wc&7);
        // consecutive tid -> consecutive q -> coalesced global, conflict-free LDS
        for (int G = tid; G < NCH * 1024; G += STH) {
            const int nl = G >> 10, f = (G >> 4) & 63, q = G & 15;
            const int wc = f >> 1, wh = f & 1;
            const float4 v = *(const float4*)(W + (size_t)(wc * N_ + n0 + nl) * 128 + wh * 64 + q * 4);
            *(float4*)(wlds + (nl * 64 + f) * 64 + (q ^ (wc & 7)) * 4) = v;
        }
        // stage X: 16 b's x NCH n's
        if (tid < NCH * 32) {
            const int nl = tid >> 5, bl = (tid >> 1) & 15, qx = tid & 1;
            const float4 v = *(const float4*)(X + (size_t)((bg * 16 + bl) * N_ + n0 + nl) * DI_ + qx * 4);
            *(float4*)(xlds + (nl * 16 + bl) * 8 + qx * 4) = v;
        }
        __syncthreads();

#pragma unroll
        for (int nl = 0; nl < NCH; nl++) {
            float4 xa[2], xb[2];
#pragma unroll
            for (int bq = 0; bq < 2; bq++) {
                const float* xp = xlds + (nl * 16 + bl0 + bq) * 8;   // wave-uniform: broadcast
                xa[bq] = *(const float4*)xp;
                xb[bq] = *(const float4*)(xp + 4);
            }
            float hat[2][8];
            const float* frag = wlds + (nl * 64 + 2 * c + h) * 64;
#pragma unroll
            for (int r = 0; r < 8; r++) {
                const int pa = ((2 * r) ^ sw) * 4;   // swizzled quad offsets
                const int pb = pa ^ 4;
                const float4 wa = *(const float4*)(frag + pa);
                const float4 wb = *(const float4*)(frag + pb);
#pragma unroll
                for (int bq = 0; bq < 2; bq++) {
                    hat[bq][r] = wa.x * xa[bq].x + wa.y * xa[bq].y + wa.z * xa[bq].z + wa.w * xa[bq].w
                               + wb.x * xb[bq].x + wb.y * xb[bq].y + wb.z * xb[bq].z + wb.w * xb[bq].w;
                }
            }
#pragma unroll
            for (int bq = 0; bq < 2; bq++) {
                float softc;
                if (t > 0) {
                    float lg = hat[bq][0]*areg[bq][0] + hat[bq][1]*areg[bq][1]
                             + hat[bq][2]*areg[bq][2] + hat[bq][3]*areg[bq][3]
                             + hat[bq][4]*areg[bq][4] + hat[bq][5]*areg[bq][5]
                             + hat[bq][6]*areg[bq][6] + hat[bq][7]*areg[bq][7];
                    lg += __shfl_xor(lg, 32, 64);      // combine i-halves (lane^32 = same c)
                    // no max-subtract: |logit| <= ~12 (||out_t||<1 per squash)
                    const float e = __expf(lg);
                    float s = e;
#pragma unroll
                    for (int m = 16; m >= 1; m >>= 1) s += __shfl_xor(s, m, 64);
                    softc = e / s;
                } else {
                    softc = 1.0f / 32.0f;              // softmax(0) over C=32
                }
#pragma unroll
                for (int r = 0; r < 8; r++) acc[bq][r] += softc * hat[bq][r];
            }
        }
    }

    // slab = bg*NSLOT + slot : [16 b][512], e = c*16 + (h*8+r)
    float* pout = partials + (size_t)(bg * NSLOT + slot) * (16 * 512);
#pragma unroll
    for (int bq = 0; bq < 2; bq++) {
        float* pb = pout + (bl0 + bq) * 512 + c * 16 + h * 8;
        *(float4*)pb       = make_float4(acc[bq][0], acc[bq][1], acc[bq][2], acc[bq][3]);
        *(float4*)(pb + 4) = make_float4(acc[bq][4], acc[bq][5], acc[bq][6], acc[bq][7]);
    }
}

// R: block = (b, e-quarter). Thread pair (e, parity) splits the slot-sum;
// squash via in-wave shuffles. Updates running acc_out; writes d_out at t==2.
__global__ __launch_bounds__(256) void caps_r(
    const float* __restrict__ partials, float* __restrict__ accb,
    float* __restrict__ out, int t)
{
    const int b   = blockIdx.x >> 2;
    const int q   = blockIdx.x & 3;
    const int tid = threadIdx.x;
    const int e   = q * 128 + (tid >> 1);
    const int p   = tid & 1;
    const int bg  = b >> 4, bl = b & 15;
    const float* base = partials + (size_t)bg * NSLOT * 8192 + (size_t)bl * 512 + e;
    float v = 0.f;
#pragma unroll 8
    for (int ch = p; ch < NSLOT; ch += 2)
        v += base[(size_t)ch * 8192];
    v += __shfl_xor(v, 1, 64);                 // combine parities
    float sq = v * v;
#pragma unroll
    for (int m = 2; m <= 16; m <<= 1) sq += __shfl_xor(sq, m, 64);  // sum over i within c
    const float scale = sq / (1.f + sq) * rsqrtf(sq + 1e-7f);
    const float ov = v * scale;
    if (p == 0) {
        const int oidx = b * 512 + e;
        if (t == 2) out[oidx] = ov;
        else        accb[oidx] = (t == 0) ? ov : (accb[oidx] + ov);
    }
}

extern "C" void kernel_launch(void* const* d_in, const int* in_sizes, int n_in,
                              void* d_out, int out_size, void* d_ws, size_t ws_size,
                              hipStream_t stream) {
    const float* X = (const float*)d_in[0];   // [B,N,DI]
    const float* W = (const float*)d_in[1];   // [C,N,DC,DI]
    float* out = (float*)d_out;               // [B,C,DC]

    // 512 slabs x 32 KB = 16.8 MB partials + 128 KB acc
    float* partials = (float*)d_ws;
    float* accb = partials + (size_t)512 * 8192;

    for (int t = 0; t < 3; t++) {
        caps_s<<<512, STH, 0, stream>>>(X, W, accb, partials, t);
        caps_r<<<256, 256, 0, stream>>>(partials, accb, out, t);
    }
}

// Round 6
// 153.390 us; speedup vs baseline: 5.3460x; 1.3802x over previous
//
#include <hip/hip_runtime.h>
#include <hip/hip_bf16.h>

#define B_  64
#define C_  32
#define N_  1152
#define DI_ 8
#define DC_ 16
#define NCH 3                // n's per staged chunk (k_hat)
#define NSLOT 128            // chunk-slots in k_hat
#define STH 512              // 8 waves

static __device__ __forceinline__ unsigned pkbf(float a, float b) {
    __hip_bfloat162 t = __float22bfloat162_rn(make_float2(a, b));
    return *reinterpret_cast<unsigned*>(&t);
}
static __device__ __forceinline__ float ubf_lo(unsigned u) {
    union { unsigned u; float f; } x; x.u = u << 16; return x.f;
}
static __device__ __forceinline__ float ubf_hi(unsigned u) {
    union { unsigned u; float f; } x; x.u = u & 0xffff0000u; return x.f;
}

// ---------------- k_hat: hat = W@x (fp32), store bf16, + s0 partials -------
// R5 caps_s structure with the t>0 softmax removed (softc=1/32 folded into a
// post-scale) and a bf16 hat store added. XOR bank swizzle kept (R5: 12.2M ->
// 2.36M conflict cycles). hat layout [b][n][512 e], e = (2c+h)*8 + r.
__global__ __launch_bounds__(STH, 2) void caps_hat(
    const float* __restrict__ X, const float* __restrict__ W,
    uint4* __restrict__ hatg, float* __restrict__ partials)
{
    __shared__ float wlds[NCH * 64 * 64];    // [nl][f=2c+h][phys quad, q^(c&7)]
    __shared__ float xlds[NCH * 16 * 8];

    const int bg   = blockIdx.x & 3;
    const int slot = blockIdx.x >> 2;
    const int tid  = threadIdx.x;
    const int w    = tid >> 6;
    const int lane = tid & 63;
    const int c    = lane & 31;
    const int h    = lane >> 5;
    const int bl0  = w * 2;
    const int le   = 2 * c + h;
    const int sw   = c & 7;

    float acc[2][8];
#pragma unroll
    for (int bq = 0; bq < 2; bq++)
#pragma unroll
        for (int r = 0; r < 8; r++) acc[bq][r] = 0.f;

    for (int cc = 0; cc < 3; cc++) {
        if (cc) __syncthreads();
        const int n0 = (slot + cc * NSLOT) * NCH;

        for (int G = tid; G < NCH * 1024; G += STH) {
            const int nl = G >> 10, f = (G >> 4) & 63, q = G & 15;
            const int wc = f >> 1, wh = f & 1;
            const float4 v = *(const float4*)(W + (size_t)(wc * N_ + n0 + nl) * 128 + wh * 64 + q * 4);
            *(float4*)(wlds + (nl * 64 + f) * 64 + (q ^ (wc & 7)) * 4) = v;
        }
        if (tid < NCH * 32) {
            const int nl = tid >> 5, bl = (tid >> 1) & 15, qx = tid & 1;
            const float4 v = *(const float4*)(X + (size_t)((bg * 16 + bl) * N_ + n0 + nl) * DI_ + qx * 4);
            *(float4*)(xlds + (nl * 16 + bl) * 8 + qx * 4) = v;
        }
        __syncthreads();

#pragma unroll
        for (int nl = 0; nl < NCH; nl++) {
            float4 xa[2], xb[2];
#pragma unroll
            for (int bq = 0; bq < 2; bq++) {
                const float* xp = xlds + (nl * 16 + bl0 + bq) * 8;
                xa[bq] = *(const float4*)xp;
                xb[bq] = *(const float4*)(xp + 4);
            }
            float hv[2][8];
            const float* frag = wlds + (nl * 64 + le) * 64;
#pragma unroll
            for (int r = 0; r < 8; r++) {
                const int pa = ((2 * r) ^ sw) * 4;
                const int pb = pa ^ 4;
                const float4 wa = *(const float4*)(frag + pa);
                const float4 wb = *(const float4*)(frag + pb);
#pragma unroll
                for (int bq = 0; bq < 2; bq++) {
                    hv[bq][r] = wa.x * xa[bq].x + wa.y * xa[bq].y + wa.z * xa[bq].z + wa.w * xa[bq].w
                              + wb.x * xb[bq].x + wb.y * xb[bq].y + wb.z * xb[bq].z + wb.w * xb[bq].w;
                }
            }
#pragma unroll
            for (int bq = 0; bq < 2; bq++) {
                uint4 hq;
                hq.x = pkbf(hv[bq][0], hv[bq][1]);
                hq.y = pkbf(hv[bq][2], hv[bq][3]);
                hq.z = pkbf(hv[bq][4], hv[bq][5]);
                hq.w = pkbf(hv[bq][6], hv[bq][7]);
                const int b = bg * 16 + bl0 + bq;
                hatg[(size_t)(b * N_ + n0 + nl) * 64 + le] = hq;
#pragma unroll
                for (int r = 0; r < 8; r++) acc[bq][r] += hv[bq][r];
            }
        }
    }

    float* pout = partials + (size_t)(bg * NSLOT + slot) * (16 * 512);
#pragma unroll
    for (int bq = 0; bq < 2; bq++) {
        float* pb = pout + (bl0 + bq) * 512 + le * 8;
        *(float4*)pb       = make_float4(acc[bq][0]*0.03125f, acc[bq][1]*0.03125f,
                                         acc[bq][2]*0.03125f, acc[bq][3]*0.03125f);
        *(float4*)(pb + 4) = make_float4(acc[bq][4]*0.03125f, acc[bq][5]*0.03125f,
                                         acc[bq][6]*0.03125f, acc[bq][7]*0.03125f);
    }
}

// ---------------- caps_route: one routing pass over materialized bf16 hat --
// block = (b, n-octant of 144), barrier-free, no LDS. Wave owns 18 n's,
// 3 loads in flight. Per-wave partial acc -> global slab [b][oct][w][512].
__global__ __launch_bounds__(STH, 2) void caps_route(
    const uint4* __restrict__ hatg, const float* __restrict__ accb,
    float* __restrict__ p2)
{
    const int b    = blockIdx.x >> 3;
    const int oct  = blockIdx.x & 7;
    const int tid  = threadIdx.x;
    const int w    = tid >> 6;
    const int lane = tid & 63;
    const int c    = lane & 31;
    const int h    = lane >> 5;
    const int le   = 2 * c + h;

    const float* ap = accb + (size_t)b * 512 + le * 8;
    const float4 a0 = *(const float4*)ap;
    const float4 a1 = *(const float4*)(ap + 4);

    float acc[8] = {0.f,0.f,0.f,0.f,0.f,0.f,0.f,0.f};
    const uint4* hb = hatg + (size_t)(b * N_ + oct * 144) * 64 + le;

    for (int k = 0; k < 6; k++) {
        uint4 v[3];
#pragma unroll
        for (int u = 0; u < 3; u++)
            v[u] = hb[(size_t)(w + 8 * (3 * k + u)) * 64];
#pragma unroll
        for (int u = 0; u < 3; u++) {
            float hv[8];
            hv[0] = ubf_lo(v[u].x); hv[1] = ubf_hi(v[u].x);
            hv[2] = ubf_lo(v[u].y); hv[3] = ubf_hi(v[u].y);
            hv[4] = ubf_lo(v[u].z); hv[5] = ubf_hi(v[u].z);
            hv[6] = ubf_lo(v[u].w); hv[7] = ubf_hi(v[u].w);
            float lg = hv[0]*a0.x + hv[1]*a0.y + hv[2]*a0.z + hv[3]*a0.w
                     + hv[4]*a1.x + hv[5]*a1.y + hv[6]*a1.z + hv[7]*a1.w;
            lg += __shfl_xor(lg, 32, 64);        // combine i-halves (same c)
            const float e = __expf(lg);          // no max-subtract: |lg| small
            float s = e;
#pragma unroll
            for (int m = 16; m >= 1; m >>= 1) s += __shfl_xor(s, m, 64);
            const float sc = e * __builtin_amdgcn_rcpf(s);
#pragma unroll
            for (int r = 0; r < 8; r++) acc[r] += sc * hv[r];
        }
    }
    float* pb = p2 + ((size_t)(b * 8 + oct) * 8 + w) * 512 + le * 8;
    *(float4*)pb       = make_float4(acc[0], acc[1], acc[2], acc[3]);
    *(float4*)(pb + 4) = make_float4(acc[4], acc[5], acc[6], acc[7]);
}

// ---------------- caps_r1: reduce k_hat's 128-slab partials (t=0) ----------
__global__ __launch_bounds__(256) void caps_r1(
    const float* __restrict__ partials, float* __restrict__ accb,
    float* __restrict__ out, int t)
{
    const int b   = blockIdx.x >> 2;
    const int q   = blockIdx.x & 3;
    const int tid = threadIdx.x;
    const int e   = q * 128 + (tid >> 1);
    const int p   = tid & 1;
    const int bg  = b >> 4, bl = b & 15;
    const float* base = partials + (size_t)bg * NSLOT * 8192 + (size_t)bl * 512 + e;
    float v = 0.f;
#pragma unroll 8
    for (int ch = p; ch < NSLOT; ch += 2)
        v += base[(size_t)ch * 8192];
    v += __shfl_xor(v, 1, 64);
    float sq = v * v;
#pragma unroll
    for (int m = 2; m <= 16; m <<= 1) sq += __shfl_xor(sq, m, 64);
    const float scale = sq / (1.f + sq) * rsqrtf(sq + 1e-7f);
    const float ov = v * scale;
    if (p == 0) {
        const int oidx = b * 512 + e;
        if (t == 2) out[oidx] = ov;
        else        accb[oidx] = (t == 0) ? ov : (accb[oidx] + ov);
    }
}

// ---------------- caps_r2: reduce caps_route's 64 slabs per b --------------
__global__ __launch_bounds__(512) void caps_r2(
    const float* __restrict__ p2, float* __restrict__ accb,
    float* __restrict__ out, int t)
{
    const int b = blockIdx.x;
    const int e = threadIdx.x;               // [c=e>>4][i=e&15]
    const float* base = p2 + (size_t)b * 32768 + e;
    float v = 0.f;
#pragma unroll 16
    for (int s = 0; s < 64; s++) v += base[s * 512];
    float sq = v * v;
#pragma unroll
    for (int m = 1; m <= 8; m <<= 1) sq += __shfl_xor(sq, m, 64);  // sum over i
    const float scale = sq / (1.f + sq) * rsqrtf(sq + 1e-7f);
    const float ov = v * scale;
    const int oidx = b * 512 + e;
    if (t == 2) out[oidx] = ov;
    else        accb[oidx] += ov;
}

// ---------------- fallback (R5 path) if ws too small -----------------------
__global__ __launch_bounds__(STH, 2) void caps_s_fb(
    const float* __restrict__ X, const float* __restrict__ W,
    const float* __restrict__ aout, float* __restrict__ partials, int t)
{
    __shared__ float wlds[NCH * 64 * 64];
    __shared__ float xlds[NCH * 16 * 8];
    const int bg = blockIdx.x & 3, slot = blockIdx.x >> 2;
    const int tid = threadIdx.x, w = tid >> 6, lane = tid & 63;
    const int c = lane & 31, h = lane >> 5, bl0 = w * 2, sw = c & 7;
    float areg[2][8] = {};
    if (t > 0) {
#pragma unroll
        for (int bq = 0; bq < 2; bq++) {
            const float* ap = aout + (size_t)(bg * 16 + bl0 + bq) * 512 + c * 16 + h * 8;
            const float4 a0 = *(const float4*)ap; const float4 a1 = *(const float4*)(ap + 4);
            areg[bq][0]=a0.x; areg[bq][1]=a0.y; areg[bq][2]=a0.z; areg[bq][3]=a0.w;
            areg[bq][4]=a1.x; areg[bq][5]=a1.y; areg[bq][6]=a1.z; areg[bq][7]=a1.w;
        }
    }
    float acc[2][8];
#pragma unroll
    for (int bq = 0; bq < 2; bq++)
#pragma unroll
        for (int r = 0; r < 8; r++) acc[bq][r] = 0.f;
    for (int cc = 0; cc < 3; cc++) {
        if (cc) __syncthreads();
        const int n0 = (slot + cc * NSLOT) * NCH;
        for (int G = tid; G < NCH * 1024; G += STH) {
            const int nl = G >> 10, f = (G >> 4) & 63, q = G & 15;
            const int wc = f >> 1, wh = f & 1;
            const float4 v = *(const float4*)(W + (size_t)(wc * N_ + n0 + nl) * 128 + wh * 64 + q * 4);
            *(float4*)(wlds + (nl * 64 + f) * 64 + (q ^ (wc & 7)) * 4) = v;
        }
        if (tid < NCH * 32) {
            const int nl = tid >> 5, bl = (tid >> 1) & 15, qx = tid & 1;
            const float4 v = *(const float4*)(X + (size_t)((bg * 16 + bl) * N_ + n0 + nl) * DI_ + qx * 4);
            *(float4*)(xlds + (nl * 16 + bl) * 8 + qx * 4) = v;
        }
        __syncthreads();
#pragma unroll
        for (int nl = 0; nl < NCH; nl++) {
            float4 xa[2], xb[2];
#pragma unroll
            for (int bq = 0; bq < 2; bq++) {
                const float* xp = xlds + (nl * 16 + bl0 + bq) * 8;
                xa[bq] = *(const float4*)xp; xb[bq] = *(const float4*)(xp + 4);
            }
            float hat[2][8];
            const float* frag = wlds + (nl * 64 + 2 * c + h) * 64;
#pragma unroll
            for (int r = 0; r < 8; r++) {
                const int pa = ((2 * r) ^ sw) * 4; const int pb = pa ^ 4;
                const float4 wa = *(const float4*)(frag + pa);
                const float4 wb = *(const float4*)(frag + pb);
#pragma unroll
                for (int bq = 0; bq < 2; bq++)
                    hat[bq][r] = wa.x*xa[bq].x + wa.y*xa[bq].y + wa.z*xa[bq].z + wa.w*xa[bq].w
                               + wb.x*xb[bq].x + wb.y*xb[bq].y + wb.z*xb[bq].z + wb.w*xb[bq].w;
            }
#pragma unroll
            for (int bq = 0; bq < 2; bq++) {
                float softc;
                if (t > 0) {
                    float lg = hat[bq][0]*areg[bq][0] + hat[bq][1]*areg[bq][1]
                             + hat[bq][2]*areg[bq][2] + hat[bq][3]*areg[bq][3]
                             + hat[bq][4]*areg[bq][4] + hat[bq][5]*areg[bq][5]
                             + hat[bq][6]*areg[bq][6] + hat[bq][7]*areg[bq][7];
                    lg += __shfl_xor(lg, 32, 64);
                    const float e = __expf(lg);
                    float s = e;
#pragma unroll
                    for (int m = 16; m >= 1; m >>= 1) s += __shfl_xor(s, m, 64);
                    softc = e / s;
                } else softc = 1.0f / 32.0f;
#pragma unroll
                for (int r = 0; r < 8; r++) acc[bq][r] += softc * hat[bq][r];
            }
        }
    }
    float* pout = partials + (size_t)(bg * NSLOT + slot) * (16 * 512);
#pragma unroll
    for (int bq = 0; bq < 2; bq++) {
        float* pb = pout + (bl0 + bq) * 512 + c * 16 + h * 8;
        *(float4*)pb       = make_float4(acc[bq][0], acc[bq][1], acc[bq][2], acc[bq][3]);
        *(float4*)(pb + 4) = make_float4(acc[bq][4], acc[bq][5], acc[bq][6], acc[bq][7]);
    }
}

extern "C" void kernel_launch(void* const* d_in, const int* in_sizes, int n_in,
                              void* d_out, int out_size, void* d_ws, size_t ws_size,
                              hipStream_t stream) {
    const float* X = (const float*)d_in[0];   // [B,N,DI]
    const float* W = (const float*)d_in[1];   // [C,N,DC,DI]
    float* out = (float*)d_out;               // [B,C,DC]

    const size_t hat_b = (size_t)B_ * N_ * 512 * 2;      // 75,497,472
    const size_t p1_b  = (size_t)512 * 8192 * 4;         // 16,777,216
    const size_t p2_b  = (size_t)B_ * 64 * 512 * 4;      //  8,388,608
    const size_t acc_b = (size_t)B_ * 512 * 4;           //    131,072

    if (ws_size >= hat_b + p1_b + p2_b + acc_b) {
        char* ws = (char*)d_ws;
        uint4* hatg = (uint4*)ws;
        float* p1   = (float*)(ws + hat_b);
        float* p2   = (float*)(ws + hat_b + p1_b);
        float* accb = (float*)(ws + hat_b + p1_b + p2_b);
        caps_hat  <<<512, STH, 0, stream>>>(X, W, hatg, p1);
        caps_r1   <<<256, 256, 0, stream>>>(p1, accb, out, 0);
        caps_route<<<512, STH, 0, stream>>>(hatg, accb, p2);
        caps_r2   <<<64, 512, 0, stream>>>(p2, accb, out, 1);
        caps_route<<<512, STH, 0, stream>>>(hatg, accb, p2);
        caps_r2   <<<64, 512, 0, stream>>>(p2, accb, out, 2);
    } else {
        float* partials = (float*)d_ws;
        float* accb = partials + (size_t)512 * 8192;
        for (int t = 0; t < 3; t++) {
            caps_s_fb<<<512, STH, 0, stream>>>(X, W, accb, partials, t);
            caps_r1  <<<256, 256, 0, stream>>>(partials, accb, out, t);
        }
    }
}